// Round 6
// baseline (384.585 us; speedup 1.0000x reference)
//
#include <hip/hip_runtime.h>
#include <hip/hip_cooperative_groups.h>

namespace cg = cooperative_groups;

namespace {
constexpr int kB = 32;
constexpr int kS = 2048;
constexpr int kH = 1024;
constexpr int kD = 1024;
constexpr int kK2 = kH + kD;        // 2048
constexpr float kWThresh = 1e-8f;   // skipped weight mass <= 2048e-8 -> err ~1e-3 << 2e-2

typedef float f32x4 __attribute__((ext_vector_type(4)));

__device__ inline float waveReduceSum(float v) {
#pragma unroll
  for (int off = 32; off > 0; off >>= 1) v += __shfl_down(v, off, 64);
  return v;
}
__device__ inline float waveReduceMax(float v) {
#pragma unroll
  for (int off = 32; off > 0; off >>= 1) v = fmaxf(v, __shfl_down(v, off, 64));
  return v;
}
}  // namespace

// One cooperative kernel, 4 phases split by grid.sync().
// grid: multiple of 8, >=256, <=1024 (4 blocks/CU co-resident guaranteed by launch_bounds).
__global__ __launch_bounds__(256, 4) void k_fused(
    const float* __restrict__ hidden, const float* __restrict__ enc,
    const int* __restrict__ lens, const float* __restrict__ W1,
    const float* __restrict__ W2, float* __restrict__ out,
    float* __restrict__ attnT, float* __restrict__ x,
    float* __restrict__ att, float* __restrict__ ctx) {
  cg::grid_group grid = cg::this_grid();
  const int t = threadIdx.x;
  const int lane = t & 63;
  const int wib = t >> 6;
  const int gwid = blockIdx.x * 4 + wib;
  const int nw = gridDim.x * 4;  // multiple of 32

  __shared__ float sred[4];
  __shared__ float swts[kS];
  __shared__ int sidx[kS];
  __shared__ int scount;

  // ---------- phase 0: x = hidden @ W1^T ----------
  for (int task = gwid; task < 1024; task += nw) {
    const int n0 = (task & 511) * 2;
    const int b0 = (task >> 9) * 16;
    const f32x4* w0v = (const f32x4*)(W1 + (size_t)n0 * kH) + lane;
    const f32x4* w1v = (const f32x4*)(W1 + (size_t)(n0 + 1) * kH) + lane;
    f32x4 w0[4], w1[4];
#pragma unroll
    for (int i = 0; i < 4; ++i) { w0[i] = w0v[64 * i]; w1[i] = w1v[64 * i]; }
    for (int b = b0; b < b0 + 16; ++b) {
      const f32x4* hv = (const f32x4*)(hidden + (size_t)b * kH) + lane;
      f32x4 s0v = {0.f, 0.f, 0.f, 0.f}, s1v = {0.f, 0.f, 0.f, 0.f};
#pragma unroll
      for (int i = 0; i < 4; ++i) {
        const f32x4 h = hv[64 * i];
        s0v += w0[i] * h;
        s1v += w1[i] * h;
      }
      const float a0 = waveReduceSum(s0v.x + s0v.y + s0v.z + s0v.w);
      const float a1 = waveReduceSum(s1v.x + s1v.y + s1v.z + s1v.w);
      if (lane == 0) {
        x[(size_t)b * kD + n0] = a0;
        x[(size_t)b * kD + n0 + 1] = a1;
      }
    }
  }
  __threadfence();
  grid.sync();

  // ---------- phase 1: att[b,s] = enc[b,s,:] . x[b,:] for s < len[b] ----------
  {
    const int b = gwid & 31;  // nw % 32 == 0 -> constant per wave
    const int len = lens[b];
    const f32x4* xv = (const f32x4*)(x + (size_t)b * kD) + lane;
    const f32x4 xr0 = xv[0], xr1 = xv[64], xr2 = xv[128], xr3 = xv[192];
    for (int tile = gwid; tile < kB * kS / 8; tile += nw) {
      const int s0 = (tile >> 5) * 8;
      if (s0 >= len) continue;  // weights exactly 0 -> never needed
#pragma unroll
      for (int c = 0; c < 2; ++c) {
        const int rs = s0 + c * 4;
        if (rs >= len) break;
        const float* eb = enc + ((size_t)b * kS + rs) * kD;
        const f32x4* r0 = (const f32x4*)(eb) + lane;
        const f32x4* r1 = (const f32x4*)(eb + kD) + lane;
        const f32x4* r2 = (const f32x4*)(eb + 2 * kD) + lane;
        const f32x4* r3 = (const f32x4*)(eb + 3 * kD) + lane;
        // hoist all 16 loads (16 KB/wave in flight) before the FMA chains
        const f32x4 e00 = r0[0], e01 = r0[64], e02 = r0[128], e03 = r0[192];
        const f32x4 e10 = r1[0], e11 = r1[64], e12 = r1[128], e13 = r1[192];
        const f32x4 e20 = r2[0], e21 = r2[64], e22 = r2[128], e23 = r2[192];
        const f32x4 e30 = r3[0], e31 = r3[64], e32 = r3[128], e33 = r3[192];
        const f32x4 d0 = e00 * xr0 + e01 * xr1 + e02 * xr2 + e03 * xr3;
        const f32x4 d1 = e10 * xr0 + e11 * xr1 + e12 * xr2 + e13 * xr3;
        const f32x4 d2 = e20 * xr0 + e21 * xr1 + e22 * xr2 + e23 * xr3;
        const f32x4 d3 = e30 * xr0 + e31 * xr1 + e32 * xr2 + e33 * xr3;
        const float a0 = waveReduceSum(d0.x + d0.y + d0.z + d0.w);
        const float a1 = waveReduceSum(d1.x + d1.y + d1.z + d1.w);
        const float a2 = waveReduceSum(d2.x + d2.y + d2.z + d2.w);
        const float a3 = waveReduceSum(d3.x + d3.y + d3.z + d3.w);
        if (lane == 0) {
          f32x4 o;
          o.x = a0; o.y = a1; o.z = a2; o.w = a3;
          *(f32x4*)(att + (size_t)b * kS + rs) = o;  // rows >= len hold garbage, never read
        }
      }
    }
  }
  __threadfence();
  grid.sync();

  // ---------- phase 2: masked softmax (==0 -> -1e10 quirk) + survivor ctx ----------
  {
    const int stride2 = gridDim.x >> 5;  // >= 8
    const int g = blockIdx.x;
    if ((g % stride2) == 0 && (g / stride2) < kB) {
      const int b = g / stride2;
      const int len = lens[b];
      float v[8];
#pragma unroll
      for (int i = 0; i < 8; ++i) {
        const int s = t + i * 256;
        const float a = (s < len) ? att[(size_t)b * kS + s] : 0.0f;
        v[i] = (a == 0.0f) ? -1e10f : a;
      }
      float m = v[0];
#pragma unroll
      for (int i = 1; i < 8; ++i) m = fmaxf(m, v[i]);
      m = waveReduceMax(m);
      if (lane == 0) sred[wib] = m;
      __syncthreads();
      m = fmaxf(fmaxf(sred[0], sred[1]), fmaxf(sred[2], sred[3]));
      __syncthreads();
      float p[8];
      float sum = 0.f;
#pragma unroll
      for (int i = 0; i < 8; ++i) {
        p[i] = __expf(v[i] - m);  // exact 0 for masked rows (non-degenerate)
        sum += p[i];
      }
      sum = waveReduceSum(sum);
      if (lane == 0) sred[wib] = sum;
      __syncthreads();
      const float inv = 1.0f / (sred[0] + sred[1] + sred[2] + sred[3]);
      if (t == 0) scount = 0;
      __syncthreads();
#pragma unroll
      for (int i = 0; i < 8; ++i) {
        const int s = t + i * 256;
        const float w = p[i] * inv;
        attnT[(size_t)s * kB + b] = w;  // output 1: attn^T [S][B]
        if (w > kWThresh) {
          const int k = atomicAdd(&scount, 1);
          sidx[k] = s;
          swts[k] = w;
        }
      }
      __syncthreads();
      const int n = scount;
      const float* ebase = enc + (size_t)b * kS * kD;
      float acc0 = 0.f, acc1 = 0.f, acc2 = 0.f, acc3 = 0.f;
      for (int k = 0; k < n; ++k) {
        const float w = swts[k];
        const float* row = ebase + (size_t)sidx[k] * kD;
        acc0 += w * row[t];
        acc1 += w * row[t + 256];
        acc2 += w * row[t + 512];
        acc3 += w * row[t + 768];
      }
      ctx[(size_t)b * kD + t] = acc0;
      ctx[(size_t)b * kD + t + 256] = acc1;
      ctx[(size_t)b * kD + t + 512] = acc2;
      ctx[(size_t)b * kD + t + 768] = acc3;
    }
  }
  __threadfence();
  grid.sync();

  // ---------- phase 3: out = tanh([ctx | hidden] @ W2^T) ----------
  for (int task = gwid; task < 512; task += nw) {
    const int n0 = task * 2;
    const f32x4* w0v = (const f32x4*)(W2 + (size_t)n0 * kK2) + lane;
    const f32x4* w1v = (const f32x4*)(W2 + (size_t)(n0 + 1) * kK2) + lane;
    f32x4 w0[8], w1[8];
#pragma unroll
    for (int i = 0; i < 8; ++i) { w0[i] = w0v[64 * i]; w1[i] = w1v[64 * i]; }
    for (int b = 0; b < kB; ++b) {
      const f32x4* cv = (const f32x4*)(ctx + (size_t)b * kD) + lane;
      const f32x4* hv = (const f32x4*)(hidden + (size_t)b * kH) + lane;
      f32x4 s0v = {0.f, 0.f, 0.f, 0.f}, s1v = {0.f, 0.f, 0.f, 0.f};
#pragma unroll
      for (int i = 0; i < 4; ++i) {
        const f32x4 a = cv[64 * i];
        s0v += w0[i] * a;
        s1v += w1[i] * a;
      }
#pragma unroll
      for (int i = 0; i < 4; ++i) {
        const f32x4 h = hv[64 * i];
        s0v += w0[i + 4] * h;
        s1v += w1[i + 4] * h;
      }
      const float a0 = waveReduceSum(s0v.x + s0v.y + s0v.z + s0v.w);
      const float a1 = waveReduceSum(s1v.x + s1v.y + s1v.z + s1v.w);
      if (lane == 0) {
        out[(size_t)b * kD + n0] = tanhf(a0);
        out[(size_t)b * kD + n0 + 1] = tanhf(a1);
      }
    }
  }
}

extern "C" void kernel_launch(void* const* d_in, const int* in_sizes, int n_in,
                              void* d_out, int out_size, void* d_ws, size_t ws_size,
                              hipStream_t stream) {
  const float* hidden = (const float*)d_in[0];  // [B, H]
  const float* enc    = (const float*)d_in[1];  // [B, S, D]
  const int*   lens   = (const int*)d_in[2];    // [B]
  const float* W1     = (const float*)d_in[3];  // [D, H]
  const float* W2     = (const float*)d_in[4];  // [D, H+D]

  float* out   = (float*)d_out;          // [B, D]
  float* attnT = out + (size_t)kB * kD;  // [S, B]

  float* ws  = (float*)d_ws;
  float* x   = ws;                       // 32768
  float* att = ws + 32768;               // 65536
  float* ctx = ws + 98304;               // 32768

  int nBlocksPerCU = 0;
  (void)hipOccupancyMaxActiveBlocksPerMultiprocessor(&nBlocksPerCU, k_fused, 256, 0);
  int nCU = 0;
  (void)hipDeviceGetAttribute(&nCU, hipDeviceAttributeMultiprocessorCount, 0);
  int grid = nBlocksPerCU * nCU;
  if (grid > 1024) grid = 1024;
  grid &= ~7;  // multiple of 8 -> nw multiple of 32 (phase-1 b mapping)
  if (grid < 256) grid = 256;

  void* args[] = {(void*)&hidden, (void*)&enc, (void*)&lens, (void*)&W1, (void*)&W2,
                  (void*)&out, (void*)&attnT, (void*)&x, (void*)&att, (void*)&ctx};
  (void)hipLaunchCooperativeKernel((const void*)k_fused, dim3(grid), dim3(256), args, 0, stream);
}

// Round 7
// 74.763 us; speedup vs baseline: 5.1441x; 5.1441x over previous
//
#include <hip/hip_runtime.h>

namespace {
constexpr int kB = 32;
constexpr int kS = 2048;
constexpr int kH = 1024;
constexpr int kD = 1024;
constexpr int kK2 = kH + kD;        // 2048
constexpr float kWThresh = 1e-8f;   // skipped weight mass <= 2048e-8 -> err ~1e-3 << 2e-2

typedef float f32x4 __attribute__((ext_vector_type(4)));

__device__ inline float waveReduceSum(float v) {
#pragma unroll
  for (int off = 32; off > 0; off >>= 1) v += __shfl_down(v, off, 64);
  return v;
}
__device__ inline float waveReduceMax(float v) {
#pragma unroll
  for (int off = 32; off > 0; off >>= 1) v = fmaxf(v, __shfl_down(v, off, 64));
  return v;
}
}  // namespace

// K1: x = hidden @ W1^T  AND  pb = hidden @ W2[:, H:]^T  (both [B, D]).
// Grid 512 blocks: waves 0..1023 do x, waves 1024..2047 do pb. Wave per 2 cols,
// b-split by 2 within each half.
__global__ __launch_bounds__(256) void k_gemv1(const float* __restrict__ hidden,
                                               const float* __restrict__ W1,
                                               const float* __restrict__ W2,
                                               float* __restrict__ x,
                                               float* __restrict__ pb) {
  const int wid_all = blockIdx.x * 4 + (threadIdx.x >> 6);  // 0..2047
  const int lane = threadIdx.x & 63;
  const bool isX = wid_all < 1024;
  const int wid = wid_all & 1023;
  const int n0 = (wid & 511) * 2;
  const int b0 = (wid >> 9) * 16;
  const float* wbase = isX ? (W1 + (size_t)n0 * kH) : (W2 + (size_t)n0 * kK2 + kH);
  const size_t wstride = isX ? (size_t)kH : (size_t)kK2;
  float* dst = isX ? x : pb;
  const f32x4* w0v = (const f32x4*)(wbase) + lane;
  const f32x4* w1v = (const f32x4*)(wbase + wstride) + lane;
  f32x4 w0[4], w1[4];
#pragma unroll
  for (int i = 0; i < 4; ++i) { w0[i] = w0v[64 * i]; w1[i] = w1v[64 * i]; }
  for (int b = b0; b < b0 + 16; ++b) {
    const f32x4* hv = (const f32x4*)(hidden + (size_t)b * kH) + lane;
    f32x4 s0v = {0.f, 0.f, 0.f, 0.f}, s1v = {0.f, 0.f, 0.f, 0.f};
#pragma unroll
    for (int i = 0; i < 4; ++i) {
      const f32x4 h = hv[64 * i];
      s0v += w0[i] * h;
      s1v += w1[i] * h;
    }
    const float a0 = waveReduceSum(s0v.x + s0v.y + s0v.z + s0v.w);
    const float a1 = waveReduceSum(s1v.x + s1v.y + s1v.z + s1v.w);
    if (lane == 0) {
      dst[(size_t)b * kD + n0] = a0;
      dst[(size_t)b * kD + n0 + 1] = a1;
    }
  }
}

// K2: att[b,s] = enc[b,s,:] . x[b,:] for s < len[b]. Wave per 4 rows, all 16
// enc loads hoisted before the FMA/reduce chains. Plain loads (L3 keeps enc warm).
__global__ __launch_bounds__(256) void k_att(const float* __restrict__ enc,
                                             const float* __restrict__ x,
                                             const int* __restrict__ lens,
                                             float* __restrict__ att) {
  const int lane = threadIdx.x & 63;
  const int wib = threadIdx.x >> 6;
  const int b = blockIdx.x & 31;
  const int s0 = (blockIdx.x >> 5) * 16 + wib * 4;
  const int len = lens[b];
  if (s0 >= len) return;  // weights exactly 0 -> scores never needed
  const f32x4* xv = (const f32x4*)(x + (size_t)b * kD) + lane;
  const f32x4 xr0 = xv[0], xr1 = xv[64], xr2 = xv[128], xr3 = xv[192];
  const float* eb = enc + ((size_t)b * kS + s0) * kD;
  const f32x4* r0 = (const f32x4*)(eb) + lane;
  const f32x4* r1 = (const f32x4*)(eb + kD) + lane;
  const f32x4* r2 = (const f32x4*)(eb + 2 * kD) + lane;
  const f32x4* r3 = (const f32x4*)(eb + 3 * kD) + lane;
  const f32x4 e00 = r0[0], e01 = r0[64], e02 = r0[128], e03 = r0[192];
  const f32x4 e10 = r1[0], e11 = r1[64], e12 = r1[128], e13 = r1[192];
  const f32x4 e20 = r2[0], e21 = r2[64], e22 = r2[128], e23 = r2[192];
  const f32x4 e30 = r3[0], e31 = r3[64], e32 = r3[128], e33 = r3[192];
  const f32x4 d0 = e00 * xr0 + e01 * xr1 + e02 * xr2 + e03 * xr3;
  const f32x4 d1 = e10 * xr0 + e11 * xr1 + e12 * xr2 + e13 * xr3;
  const f32x4 d2 = e20 * xr0 + e21 * xr1 + e22 * xr2 + e23 * xr3;
  const f32x4 d3 = e30 * xr0 + e31 * xr1 + e32 * xr2 + e33 * xr3;
  const float a0 = waveReduceSum(d0.x + d0.y + d0.z + d0.w);
  const float a1 = waveReduceSum(d1.x + d1.y + d1.z + d1.w);
  const float a2 = waveReduceSum(d2.x + d2.y + d2.z + d2.w);
  const float a3 = waveReduceSum(d3.x + d3.y + d3.z + d3.w);
  if (lane == 0) {
    f32x4 o;
    o.x = a0; o.y = a1; o.z = a2; o.w = a3;
    *(f32x4*)(att + (size_t)b * kS + s0) = o;  // rows >= len: garbage, never read
  }
}

// K3: masked softmax (==0 -> -1e10 quirk) + survivor-gathered ctx. Block per batch.
__global__ __launch_bounds__(1024) void k_smctx(const float* __restrict__ att,
                                                const int* __restrict__ lens,
                                                const float* __restrict__ enc,
                                                float* __restrict__ attnT,
                                                float* __restrict__ ctx) {
  const int b = blockIdx.x;
  const int t = threadIdx.x;
  const int len = lens[b];
  __shared__ float sred[16];
  __shared__ float swts[kS];
  __shared__ int sidx[kS];
  __shared__ int scount;

  const float a0 = (t < len) ? att[(size_t)b * kS + t] : 0.0f;
  const float a1 = (t + 1024 < len) ? att[(size_t)b * kS + t + 1024] : 0.0f;
  const float v0 = (a0 == 0.0f) ? -1e10f : a0;
  const float v1 = (a1 == 0.0f) ? -1e10f : a1;

  float m = waveReduceMax(fmaxf(v0, v1));
  if ((t & 63) == 0) sred[t >> 6] = m;
  __syncthreads();
  if (t < 16) {
    float mm = sred[t];
#pragma unroll
    for (int off = 8; off > 0; off >>= 1) mm = fmaxf(mm, __shfl_down(mm, off, 64));
    if (t == 0) sred[0] = mm;
  }
  __syncthreads();
  m = sred[0];
  __syncthreads();

  float p0 = __expf(v0 - m), p1 = __expf(v1 - m);
  float sum = waveReduceSum(p0 + p1);
  if ((t & 63) == 0) sred[t >> 6] = sum;
  __syncthreads();
  if (t < 16) {
    float ss = sred[t];
#pragma unroll
    for (int off = 8; off > 0; off >>= 1) ss += __shfl_down(ss, off, 64);
    if (t == 0) sred[0] = ss;
  }
  __syncthreads();
  const float inv = 1.0f / sred[0];
  p0 *= inv;
  p1 *= inv;

  attnT[(size_t)t * kB + b] = p0;              // output 1: attn^T [S][B]
  attnT[(size_t)(t + 1024) * kB + b] = p1;

  if (t == 0) scount = 0;
  __syncthreads();
  if (p0 > kWThresh) { const int k = atomicAdd(&scount, 1); sidx[k] = t;        swts[k] = p0; }
  if (p1 > kWThresh) { const int k = atomicAdd(&scount, 1); sidx[k] = t + 1024; swts[k] = p1; }
  __syncthreads();

  const int n = scount;
  const float* ebase = enc + (size_t)b * kS * kD + t;
  float acc = 0.f;
  int k = 0;
  for (; k + 4 <= n; k += 4) {
    const float e0 = ebase[(size_t)sidx[k + 0] * kD];
    const float e1 = ebase[(size_t)sidx[k + 1] * kD];
    const float e2 = ebase[(size_t)sidx[k + 2] * kD];
    const float e3 = ebase[(size_t)sidx[k + 3] * kD];
    acc += swts[k + 0] * e0 + swts[k + 1] * e1 + swts[k + 2] * e2 + swts[k + 3] * e3;
  }
  for (; k < n; ++k) acc += swts[k] * ebase[(size_t)sidx[k] * kD];
  ctx[(size_t)b * kD + t] = acc;
}

// K4: out = tanh(ctx @ W2[:, :H]^T + pb). Wave per 2 cols, b-split by 2 (grid 256).
__global__ __launch_bounds__(256) void k_out(const float* __restrict__ ctx,
                                             const float* __restrict__ pb,
                                             const float* __restrict__ W2,
                                             float* __restrict__ out) {
  const int wid = (blockIdx.x * blockDim.x + threadIdx.x) >> 6;  // 0..1023
  const int lane = threadIdx.x & 63;
  const int n0 = (wid & 511) * 2;
  const int b0 = (wid >> 9) * 16;
  const f32x4* w0v = (const f32x4*)(W2 + (size_t)n0 * kK2) + lane;
  const f32x4* w1v = (const f32x4*)(W2 + (size_t)(n0 + 1) * kK2) + lane;
  f32x4 w0[4], w1[4];
#pragma unroll
  for (int i = 0; i < 4; ++i) { w0[i] = w0v[64 * i]; w1[i] = w1v[64 * i]; }
  for (int b = b0; b < b0 + 16; ++b) {
    const f32x4* cv = (const f32x4*)(ctx + (size_t)b * kD) + lane;
    f32x4 s0v = {0.f, 0.f, 0.f, 0.f}, s1v = {0.f, 0.f, 0.f, 0.f};
#pragma unroll
    for (int i = 0; i < 4; ++i) {
      const f32x4 a = cv[64 * i];
      s0v += w0[i] * a;
      s1v += w1[i] * a;
    }
    const float a0 = waveReduceSum(s0v.x + s0v.y + s0v.z + s0v.w);
    const float a1 = waveReduceSum(s1v.x + s1v.y + s1v.z + s1v.w);
    if (lane == 0) {
      out[(size_t)b * kD + n0] = tanhf(a0 + pb[(size_t)b * kD + n0]);
      out[(size_t)b * kD + n0 + 1] = tanhf(a1 + pb[(size_t)b * kD + n0 + 1]);
    }
  }
}

extern "C" void kernel_launch(void* const* d_in, const int* in_sizes, int n_in,
                              void* d_out, int out_size, void* d_ws, size_t ws_size,
                              hipStream_t stream) {
  const float* hidden = (const float*)d_in[0];  // [B, H]
  const float* enc    = (const float*)d_in[1];  // [B, S, D]
  const int*   lens   = (const int*)d_in[2];    // [B]
  const float* W1     = (const float*)d_in[3];  // [D, H]
  const float* W2     = (const float*)d_in[4];  // [D, H+D]

  float* out   = (float*)d_out;          // [B, D]
  float* attnT = out + (size_t)kB * kD;  // [S, B]

  float* ws  = (float*)d_ws;
  float* x   = ws;              // 32768
  float* att = ws + 32768;      // 65536
  float* ctx = ws + 98304;      // 32768
  float* pb  = ws + 131072;     // 32768

  k_gemv1<<<512, 256, 0, stream>>>(hidden, W1, W2, x, pb);
  k_att<<<kB * (kS / 16), 256, 0, stream>>>(enc, x, lens, att);
  k_smctx<<<kB, 1024, 0, stream>>>(att, lens, enc, attnT, ctx);
  k_out<<<256, 256, 0, stream>>>(ctx, pb, W2, out);
}